// Round 4
// baseline (5325.990 us; speedup 1.0000x reference)
//
#include <hip/hip_runtime.h>
#include <stdint.h>
#include <stddef.h>

#define T_SEQ  512
#define NBATCH 64
#define EMBED  512
#define HIDDEN 1024
#define VOCAB  32000
#define NWG    128
#define NTHR   256
#define AGENT  __HIP_MEMORY_SCOPE_AGENT
#define RING   260                    // h ring slots: [64][ h1(1024) | h0(1024) ] bf16
#define SLOT_E (NBATCH * 2048)
#define BOUND  250                    // max L0 lead over L1 (ring-WAR bound, < RING-2)

#define RST   66                      // reduce-buffer row stride (floats)
#define PBUF  (64 * RST)              // one wave's partial: 64 rows x 64 batch

// counter line for (layer l, step t); init counter = CNT(0, 512)
#define CNT(l, t) (cnt + ((((t) << 1) | (l)) << 5))

typedef __attribute__((ext_vector_type(8))) short short8;
typedef __attribute__((ext_vector_type(4))) float f32x4;

__device__ __forceinline__ unsigned short f2bf(float x) {
  union { float f; unsigned u; } v; v.f = x;
  unsigned r = v.u + 0x7FFFu + ((v.u >> 16) & 1u);   // round-to-nearest-even
  return (unsigned short)(r >> 16);
}
__device__ __forceinline__ float sigm(float x) { return 1.0f / (1.0f + __expf(-x)); }
__device__ __forceinline__ float tanh_(float x) {
  float e = __expf(2.0f * x);
  return 1.0f - 2.0f / (e + 1.0f);
}

__device__ __forceinline__ void wait_ge(unsigned* p, unsigned tgt) {
  while (__hip_atomic_load(p, __ATOMIC_RELAXED, AGENT) < tgt)
    __builtin_amdgcn_s_sleep(1);
  __builtin_amdgcn_fence(__ATOMIC_ACQUIRE, "workgroup");  // compiler ordering
  asm volatile("" ::: "memory");
}

// ---------------- embedding gather + bf16 cast: xs[t][b][e] ----------------
__global__ void embed_k(const int* __restrict__ texts, const float* __restrict__ emb,
                        unsigned short* __restrict__ xs) {
  const int bid = blockIdx.x;          // t*64 + b
  const int t = bid >> 6, b = bid & 63;
  const int row = texts[b * T_SEQ + t];
  const float* src = emb + (size_t)row * EMBED;
  const int e = threadIdx.x * 2;
  float2 v = *(const float2*)(src + e);
  unsigned pk = (unsigned)f2bf(v.x) | ((unsigned)f2bf(v.y) << 16);
  *(unsigned*)(xs + (size_t)bid * EMBED + e) = pk;
}

// ---------------- one LSTM layer, persistent, weights in VGPRs ----------------
// WG w owns dims [w*16, w*16+16) -> 64 gate rows as 4 m-tiles (mt = gate).
// 4 waves K-split. Ring slot s: lo = h1(s-1), hi = h0(s-1).
// L0 step t: reads slot[t].hi (h0(t-1)) + xs[t]; writes slot[t+1].hi. Arrives cnt0[t].
// L1 step t: reads slot[t].lo (h1(t-1)) + slot[t+1].hi (h0(t)); writes slot[t+1].lo.
template<int LAYER>
__device__ __forceinline__ void run_layer(
    const unsigned short* __restrict__ xs_all,
    unsigned short* __restrict__ state,
    unsigned* __restrict__ cnt,
    const float* __restrict__ W0, const float* __restrict__ W1,
    const float* __restrict__ W2, const float* __restrict__ W3,
    const float* __restrict__ B0, const float* __restrict__ B1,
    const float* __restrict__ B2, const float* __restrict__ B3,
    float* buf, int w, int tid)
{
  constexpr int K  = LAYER ? 2048 : 1536;
  constexpr int KT = K / 128;              // 16 / 12 K-tiles per wave
  const int lane = tid & 63;
  const int wid  = tid >> 6;               // wave id = K-quarter
  const int ln   = lane & 15;
  const int qq   = lane >> 4;
  const int d0   = (tid & 7) * 2;          // dim pair within WG's 16 dims
  const int bp   = (tid >> 3) * 2;         // batch pair
  const int gk0  = w * 16 + d0;

  // ---- stage weights into VGPRs: wreg[kt][mt], mt = gate, rows = dim ln ----
  short8 wreg[KT][4];
  const float* Wg[4] = {W0, W1, W2, W3};
  #pragma unroll
  for (int mt = 0; mt < 4; ++mt) {
    const float* row = Wg[mt] + (size_t)(w * 16 + ln) * K;
    #pragma unroll
    for (int kt = 0; kt < KT; ++kt) {
      int col;
      if (LAYER == 1) col = wid * 512 + kt * 32;
      else col = (kt < 4) ? (1024 + wid * 128 + kt * 32) : (wid * 256 + (kt - 4) * 32);
      col += qq * 8;
      f32x4 lo = *(const f32x4*)(row + col);
      f32x4 hi = *(const f32x4*)(row + col + 4);
      short8 v;
      v[0] = (short)f2bf(lo[0]); v[1] = (short)f2bf(lo[1]);
      v[2] = (short)f2bf(lo[2]); v[3] = (short)f2bf(lo[3]);
      v[4] = (short)f2bf(hi[0]); v[5] = (short)f2bf(hi[1]);
      v[6] = (short)f2bf(hi[2]); v[7] = (short)f2bf(hi[3]);
      wreg[kt][mt] = v;
    }
  }

  float bs[4][2];
  #pragma unroll
  for (int g = 0; g < 4; ++g) {
    const float* Bg = (g == 0) ? B0 : (g == 1) ? B1 : (g == 2) ? B2 : B3;
    bs[g][0] = Bg[gk0]; bs[g][1] = Bg[gk0 + 1];
  }
  float cst[2][2] = {{0.f, 0.f}, {0.f, 0.f}};

  wait_ge(CNT(0, 512), NWG);               // slot 0 zeroed everywhere

  for (int t = 0; t < T_SEQ; ++t) {
    const int so  = t % RING;
    const int so1 = (t + 1) % RING;
    const unsigned short* slotT  = state + (size_t)so  * SLOT_E;
    const unsigned short* slotT1 = state + (size_t)so1 * SLOT_E;
    f32x4 acc[4][4] = {};

    if constexpr (LAYER == 0) {
      const unsigned short* xrow = xs_all + (size_t)t * (NBATCH * EMBED);
      // x-phase (static input) BEFORE poll: overlaps rendezvous latency
      #pragma unroll
      for (int kt = 0; kt < 4; ++kt) {
        const int bc = wid * 128 + kt * 32 + qq * 8;
        short8 bf[4];
        #pragma unroll
        for (int nt = 0; nt < 4; ++nt)
          bf[nt] = *(const short8*)(xrow + (size_t)(nt * 16 + ln) * EMBED + bc);
        #pragma unroll
        for (int mt = 0; mt < 4; ++mt)
          #pragma unroll
          for (int nt = 0; nt < 4; ++nt)
            acc[mt][nt] = __builtin_amdgcn_mfma_f32_16x16x32_bf16(
                wreg[kt][mt], bf[nt], acc[mt][nt], 0, 0, 0);
      }
      if (t > 0) wait_ge(CNT(0, t - 1), 64);   // peer h0(t-1) ready
      const unsigned short* hbase = slotT + 1024;
      #pragma unroll
      for (int kt = 4; kt < KT; ++kt) {
        const int hc = wid * 256 + (kt - 4) * 32 + qq * 8;
        short8 bf[4];
        #pragma unroll
        for (int nt = 0; nt < 4; ++nt)
          bf[nt] = *(const short8*)(hbase + (size_t)(nt * 16 + ln) * 2048 + hc);
        #pragma unroll
        for (int mt = 0; mt < 4; ++mt)
          #pragma unroll
          for (int nt = 0; nt < 4; ++nt)
            acc[mt][nt] = __builtin_amdgcn_mfma_f32_16x16x32_bf16(
                wreg[kt][mt], bf[nt], acc[mt][nt], 0, 0, 0);
      }
    } else {
      // waves 0-1 read h1(t-1) (cols 0..1023 of slot t); waves 2-3 read h0(t)
      // (cols 1024..2047 of slot t+1). Poll only what this wave needs.
      if (wid >= 2)      wait_ge(CNT(0, t), 64);
      else if (t > 0)    wait_ge(CNT(1, t - 1), 64);
      const unsigned short* base = (wid < 2) ? slotT : slotT1;
      #pragma unroll
      for (int kt = 0; kt < KT; ++kt) {
        const int c = wid * 512 + kt * 32 + qq * 8;
        short8 bf[4];
        #pragma unroll
        for (int nt = 0; nt < 4; ++nt)
          bf[nt] = *(const short8*)(base + (size_t)(nt * 16 + ln) * 2048 + c);
        #pragma unroll
        for (int mt = 0; mt < 4; ++mt)
          #pragma unroll
          for (int nt = 0; nt < 4; ++nt)
            acc[mt][nt] = __builtin_amdgcn_mfma_f32_16x16x32_bf16(
                wreg[kt][mt], bf[nt], acc[mt][nt], 0, 0, 0);
      }
    }

    // ---- each wave writes its K-partial to its own LDS buffer ----
    {
      float* bb = buf + wid * PBUF;
      #pragma unroll
      for (int mt = 0; mt < 4; ++mt)
        #pragma unroll
        for (int nt = 0; nt < 4; ++nt)
          #pragma unroll
          for (int j = 0; j < 4; ++j)
            bb[(mt * 16 + qq * 4 + j) * RST + nt * 16 + ln] = acc[mt][nt][j];
    }
    __syncthreads();

    // ---- gate math: this thread owns dims (gk0, gk0+1) x batches (bp, bp+1) ----
    float gv[4][2][2];
    #pragma unroll
    for (int gt = 0; gt < 4; ++gt)
      #pragma unroll
      for (int dd = 0; dd < 2; ++dd) {
        float sx = bs[gt][dd], sy = bs[gt][dd];
        #pragma unroll
        for (int p = 0; p < 4; ++p) {
          float2 v = *(const float2*)&buf[p * PBUF + (gt * 16 + d0 + dd) * RST + bp];
          sx += v.x; sy += v.y;
        }
        gv[gt][dd][0] = sx; gv[gt][dd][1] = sy;
      }

    if (LAYER == 0 && t >= BOUND)
      wait_ge(CNT(1, t - BOUND), 64);       // ring WAR: don't lead L1 by > BOUND

    unsigned* su = (unsigned*)state;
    const size_t obase = (size_t)so1 * SLOT_E + (LAYER == 0 ? 1024 : 0) + gk0;
    #pragma unroll
    for (int s2 = 0; s2 < 2; ++s2) {
      cst[0][s2] = sigm(gv[0][0][s2]) * cst[0][s2] + sigm(gv[1][0][s2]) * tanh_(gv[3][0][s2]);
      cst[1][s2] = sigm(gv[0][1][s2]) * cst[1][s2] + sigm(gv[1][1][s2]) * tanh_(gv[3][1][s2]);
      const float h0v = sigm(gv[2][0][s2]) * tanh_(cst[0][s2]);
      const float h1v = sigm(gv[2][1][s2]) * tanh_(cst[1][s2]);
      const unsigned pk = (unsigned)f2bf(h0v) | ((unsigned)f2bf(h1v) << 16);
      __hip_atomic_store(su + ((obase + (size_t)(bp + s2) * 2048) >> 1), pk,
                         __ATOMIC_RELAXED, AGENT);
    }
    __syncthreads();   // drains all waves' sc1 stores; also protects LDS reuse
    if (tid == 0)
      __hip_atomic_fetch_add(CNT(LAYER, t), 1u, __ATOMIC_RELAXED, AGENT);
  }
}

__launch_bounds__(NTHR, 1)
__global__ void lstm_k(const unsigned short* __restrict__ xs,
                       unsigned short* __restrict__ state,
                       unsigned* __restrict__ cnt,
                       const float* __restrict__ Wf0, const float* __restrict__ Wi0,
                       const float* __restrict__ Wo0, const float* __restrict__ Wc0,
                       const float* __restrict__ bf0, const float* __restrict__ bi0,
                       const float* __restrict__ bo0, const float* __restrict__ bc0,
                       const float* __restrict__ Wf1, const float* __restrict__ Wi1,
                       const float* __restrict__ Wo1, const float* __restrict__ Wc1,
                       const float* __restrict__ bf1, const float* __restrict__ bi1,
                       const float* __restrict__ bo1, const float* __restrict__ bc1)
{
  __shared__ __align__(16) float buf[4 * PBUF];   // 67.6 KB
  const int tid = threadIdx.x;
  const int gw  = blockIdx.x;

  // zero ring slot 0 (h0(-1), h1(-1) = 0), then init rendezvous
  {
    unsigned* su = (unsigned*)state;
    const int idx = gw * NTHR + tid;               // 32768 threads, 65536 u32
    __hip_atomic_store(su + idx,         0u, __ATOMIC_RELAXED, AGENT);
    __hip_atomic_store(su + 32768 + idx, 0u, __ATOMIC_RELAXED, AGENT);
    __syncthreads();
    if (tid == 0)
      __hip_atomic_fetch_add(CNT(0, 512), 1u, __ATOMIC_RELAXED, AGENT);
  }

  if (gw < 64)
    run_layer<0>(xs, state, cnt, Wf0, Wi0, Wo0, Wc0, bf0, bi0, bo0, bc0,
                 buf, gw, tid);
  else
    run_layer<1>(nullptr, state, cnt, Wf1, Wi1, Wo1, Wc1, bf1, bi1, bo1, bc1,
                 buf, gw - 64, tid);
}

// ---------------- final projection: y[b][v] = h1(511) . Wy[v] + by[v] ----------------
__global__ void final_k(const float* __restrict__ Wy,                // [VOCAB][1024] f32
                        const unsigned short* __restrict__ hlast,    // [64][2048] lo-half
                        const float* __restrict__ by,
                        float* __restrict__ out)                     // [64][VOCAB] f32
{
  const int tid = threadIdx.x, lane = tid & 63, wid = tid >> 6;
  const int ln = lane & 15, qq = lane >> 4;
  const int vbase = (blockIdx.x * 4 + wid) * 16;
  f32x4 acc[4] = {};
  const float* arow = Wy + (size_t)(vbase + ln) * HIDDEN;
  for (int kt = 0; kt < 32; ++kt) {
    const int kk = kt * 32 + qq * 8;
    f32x4 lo = *(const f32x4*)(arow + kk);
    f32x4 hi = *(const f32x4*)(arow + kk + 4);
    short8 a;
    a[0] = (short)f2bf(lo[0]); a[1] = (short)f2bf(lo[1]);
    a[2] = (short)f2bf(lo[2]); a[3] = (short)f2bf(lo[3]);
    a[4] = (short)f2bf(hi[0]); a[5] = (short)f2bf(hi[1]);
    a[6] = (short)f2bf(hi[2]); a[7] = (short)f2bf(hi[3]);
    #pragma unroll
    for (int nt = 0; nt < 4; ++nt) {
      short8 bv = *(const short8*)(hlast + (size_t)(nt * 16 + ln) * 2048 + kk);
      acc[nt] = __builtin_amdgcn_mfma_f32_16x16x32_bf16(a, bv, acc[nt], 0, 0, 0);
    }
  }
  const int v0 = vbase + qq * 4;
  const f32x4 bias = *(const f32x4*)(by + v0);
  #pragma unroll
  for (int nt = 0; nt < 4; ++nt) {
    const int bb = nt * 16 + ln;
    f32x4 r = acc[nt] + bias;
    *(f32x4*)(out + (size_t)bb * VOCAB + v0) = r;
  }
}

// ---------------- host ----------------
extern "C" void kernel_launch(void* const* d_in, const int* in_sizes, int n_in,
                              void* d_out, int out_size, void* d_ws, size_t ws_size,
                              hipStream_t stream) {
  (void)in_sizes; (void)n_in; (void)out_size; (void)ws_size;
  const int*   texts = (const int*)d_in[0];
  const float* emb   = (const float*)d_in[1];
  const float* Wf0 = (const float*)d_in[2];  const float* bf0 = (const float*)d_in[3];
  const float* Wi0 = (const float*)d_in[4];  const float* bi0 = (const float*)d_in[5];
  const float* Wo0 = (const float*)d_in[6];  const float* bo0 = (const float*)d_in[7];
  const float* Wc0 = (const float*)d_in[8];  const float* bc0 = (const float*)d_in[9];
  const float* Wf1 = (const float*)d_in[10]; const float* bf1 = (const float*)d_in[11];
  const float* Wi1 = (const float*)d_in[12]; const float* bi1 = (const float*)d_in[13];
  const float* Wo1 = (const float*)d_in[14]; const float* bo1 = (const float*)d_in[15];
  const float* Wc1 = (const float*)d_in[16]; const float* bc1 = (const float*)d_in[17];
  const float* Wy  = (const float*)d_in[18]; const float* by  = (const float*)d_in[19];

  char* ws = (char*)d_ws;
  // ws layout (bytes): [0] counters (256KB) | 262144 state ring 260x64x2048 bf16
  // (68,157,440) | 68,419,584 xs 512x64x512 bf16 (33,554,432) | end 101,974,016
  unsigned*       cnt   = (unsigned*)ws;
  unsigned short* state = (unsigned short*)(ws + 262144);
  unsigned short* xs    = (unsigned short*)(ws + 262144 + (size_t)RING * SLOT_E * 2);
  float* out = (float*)d_out;

  hipMemsetAsync(cnt, 0, 135168, stream);   // reset all step counters every call
  embed_k<<<T_SEQ * NBATCH, 256, 0, stream>>>(texts, emb, xs);
  lstm_k<<<NWG, NTHR, 0, stream>>>(xs, state, cnt,
                                   Wf0, Wi0, Wo0, Wc0, bf0, bi0, bo0, bc0,
                                   Wf1, Wi1, Wo1, Wc1, bf1, bi1, bo1, bc1);
  // h1(511) lives in slot 512 % RING = 252, cols 0..1023
  final_k<<<VOCAB / 64, 256, 0, stream>>>(
      Wy, state + (size_t)(T_SEQ % RING) * SLOT_E, by, out);
}